// Round 8
// baseline (205.426 us; speedup 1.0000x reference)
//
#include <hip/hip_runtime.h>
#include <hip/hip_bf16.h>

#define IN_FEATURES   4096
#define LOCAL_FEATURES  32
#define KERNEL_SIZE     64
#define FOLD_NUM      4096
#define BATCH          256

// padded geometry for aligned loads
#define XROW 4192               // 4096 + 96 pad (bf16 elems), row stride 8384 B (16B-mult)
#define KPAD 96                 // K padded 64 -> 96: slot base (f & ~7) keeps 16B alignment
#define EROW 2052               // epilogue LDS row stride in f32 (2048 + 4 pad)

using bf16 = __hip_bfloat16;
typedef __attribute__((ext_vector_type(8))) short bf16x8;
typedef __attribute__((ext_vector_type(4))) float f32x4;

static __device__ __forceinline__ short bfbits(float v) {
    __hip_bfloat16 h = __float2bfloat16(v);
    return *reinterpret_cast<short*>(&h);
}

// ---------- fused prep: bid<2048 -> weight transpose (2 folds/block);
//                        bid>=2048 -> x convert+pad ----------
// wt[f][n][kk] = W[f][kk - (f&7)][n] for (f&7) <= kk < (f&7)+64, else 0.
__global__ void prep_kernel(const float* __restrict__ x, const float* __restrict__ w,
                            bf16* __restrict__ xb, bf16* __restrict__ wt) {
    __shared__ bf16 lds[2][32][KPAD];                  // 12288 B
    const int t = threadIdx.x;

    if (blockIdx.x >= 2048) {
        // ---- convert x f32 [256][4096] -> bf16 [256][4192], zero pad ----
        const int u   = (blockIdx.x - 2048) * 256 + t; // 134144 = 524*256 vec8 units
        const int row = u / 524;
        const int c8  = (u - row * 524) * 8;
        bf16x8 o;
        if (c8 < 4096) {
            const float4 a = *reinterpret_cast<const float4*>(x + (size_t)row * 4096 + c8);
            const float4 b = *reinterpret_cast<const float4*>(x + (size_t)row * 4096 + c8 + 4);
            o[0] = bfbits(a.x); o[1] = bfbits(a.y); o[2] = bfbits(a.z); o[3] = bfbits(a.w);
            o[4] = bfbits(b.x); o[5] = bfbits(b.y); o[6] = bfbits(b.z); o[7] = bfbits(b.w);
        } else {
            o = (bf16x8){0,0,0,0,0,0,0,0};
        }
        *reinterpret_cast<bf16x8*>(xb + (size_t)row * XROW + c8) = o;
        return;
    }

    // ---- weight transpose+shift for folds f0, f0+1 ----
    const int f0 = blockIdx.x * 2;
    {
        uint4* z = reinterpret_cast<uint4*>(&lds[0][0][0]);
        const uint4 zz = {0, 0, 0, 0};
        z[t] = zz; z[t + 256] = zz; z[t + 512] = zz;   // 768 * 16B = 12288 B
    }
    __syncthreads();
    {
        const int fp  = t >> 7;                        // fold-in-block 0/1
        const int tt  = t & 127;
        const int shf = (f0 + fp) & 7;
        const float* src = w + (size_t)(f0 + fp) * 2048 + tt * 16;
        #pragma unroll
        for (int v = 0; v < 4; ++v) {
            const float4 val = *reinterpret_cast<const float4*>(src + v * 4);
            const int e  = tt * 16 + v * 4;            // flat elem, n fastest
            const int k  = e >> 5;
            const int n0 = e & 31;
            lds[fp][n0 + 0][k + shf] = __float2bfloat16(val.x);
            lds[fp][n0 + 1][k + shf] = __float2bfloat16(val.y);
            lds[fp][n0 + 2][k + shf] = __float2bfloat16(val.z);
            lds[fp][n0 + 3][k + shf] = __float2bfloat16(val.w);
        }
    }
    __syncthreads();
    if (t < 192) {
        const int fp = t / 96;
        const int tt = t - fp * 96;
        const int n  = tt / 3;
        const int k0 = (tt - n * 3) * 32;
        const uint4* lp = reinterpret_cast<const uint4*>(&lds[fp][n][k0]);
        uint4* gp = reinterpret_cast<uint4*>(wt + ((size_t)(f0 + fp) * 32 + n) * KPAD + k0);
        gp[0] = lp[0]; gp[1] = lp[1]; gp[2] = lp[2]; gp[3] = lp[3];
    }
}

// ---------- main: block = 64 folds x 16 rows (512 thr); wave = 8 folds x 16 rows ----
// Writes 8KB contiguous per batch row; quarter-sized LDS epilogue; 3 waves/SIMD.
__global__ __launch_bounds__(512, 3)
void local_linear_main(const bf16* __restrict__ xb, const bf16* __restrict__ wt,
                       const float* __restrict__ bias, float* __restrict__ out)
{
    __shared__ float eld[4 * EROW];          // 32.8 KB (4 rows x 2048 f32 + pad)

    const int bid  = blockIdx.x;             // 1024
    const int t    = threadIdx.x;            // 512
    const int lane = t & 63;
    const int wid  = t >> 6;                 // 0..7

    // 16 b-tiles of one f-group share bid%8 -> same XCD L2 for wt reuse
    const int fg   = bid & 63;
    const int bt   = bid >> 6;               // 0..15
    const int f0   = fg * 64;
    const int fw   = f0 + wid * 8;           // wave's 8 folds; fw % 8 == 0
    const int lrow = lane & 15;
    const int kgrp = lane >> 4;
    const int b0   = bt * 16;
    const int brow = b0 + lrow;

    // B-frags (x window): single aligned base (fw%8==0), shared by all 8 folds
    bf16x8 bfr[3];
    {
        const bf16* xbase = xb + (size_t)brow * XROW + fw + kgrp * 8;
        #pragma unroll
        for (int ks = 0; ks < 3; ++ks)
            bfr[ks] = *reinterpret_cast<const bf16x8*>(xbase + ks * 32);
    }

    f32x4 acc[8][2];
    #pragma unroll
    for (int i = 0; i < 8; ++i)
        #pragma unroll
        for (int mt = 0; mt < 2; ++mt)
            acc[i][mt] = (f32x4){0.f, 0.f, 0.f, 0.f};

    #pragma unroll
    for (int i = 0; i < 8; ++i) {
        const bf16* wbase = wt + (size_t)(fw + i) * (32 * KPAD) + kgrp * 8;
        bf16x8 afr[2][3];
        #pragma unroll
        for (int mt = 0; mt < 2; ++mt)
            #pragma unroll
            for (int ks = 0; ks < 3; ++ks)
                afr[mt][ks] = *reinterpret_cast<const bf16x8*>(
                    wbase + (mt * 16 + lrow) * KPAD + ks * 32);
        #pragma unroll
        for (int ks = 0; ks < 3; ++ks)
            #pragma unroll
            for (int mt = 0; mt < 2; ++mt)
                acc[i][mt] = __builtin_amdgcn_mfma_f32_16x16x32_bf16(
                    afr[mt][ks], bfr[ks], acc[i][mt], 0, 0, 0);
    }

    // bias: lane holds n = mt*16 + kgrp*4 + r for fold fw+i
    #pragma unroll
    for (int i = 0; i < 8; ++i)
        #pragma unroll
        for (int mt = 0; mt < 2; ++mt) {
            const float4 bv = *reinterpret_cast<const float4*>(
                bias + (fw + i) * 32 + mt * 16 + kgrp * 4);
            acc[i][mt][0] += bv.x; acc[i][mt][1] += bv.y;
            acc[i][mt][2] += bv.z; acc[i][mt][3] += bv.w;
        }

    // ---- epilogue: 4 quarters of 4 rows x 2048 f32 through LDS ----
    const size_t outcol0 = (size_t)f0 * 32;
    #pragma unroll
    for (int q = 0; q < 4; ++q) {
        __syncthreads();                     // protect eld reuse
        if ((lrow >> 2) == q) {
            #pragma unroll
            for (int i = 0; i < 8; ++i)
                #pragma unroll
                for (int mt = 0; mt < 2; ++mt)
                    *reinterpret_cast<f32x4*>(
                        &eld[(lrow & 3) * EROW + (wid * 8 + i) * 32 + mt * 16 + kgrp * 4])
                        = acc[i][mt];
        }
        __syncthreads();
        // LDS -> global: 2KB contiguous per wave-instruction, 8KB per row
        #pragma unroll
        for (int j = 0; j < 4; ++j) {
            const int Lf  = (j * 512 + t) * 4;        // f32 idx in quarter (0..8191)
            const int row = Lf >> 11;                  // 0..3
            const int col = Lf & 2047;
            const f32x4 v = *reinterpret_cast<const f32x4*>(&eld[row * EROW + col]);
            const size_t g = (size_t)(b0 + q * 4 + row) * (FOLD_NUM * 32) + outcol0 + col;
            __builtin_nontemporal_store(v, reinterpret_cast<f32x4*>(out + g));
        }
    }
}

// ---------- fallback (round-2 kernel, known-passing) ----------
#define LDA 80
#define LDB 80
__global__ __launch_bounds__(256, 2)
void local_linear_kernel(const float* __restrict__ x, const float* __restrict__ w,
                         const float* __restrict__ bias, float* __restrict__ out)
{
    __shared__ bf16 As[BATCH * LDA];
    __shared__ bf16 Bs[LOCAL_FEATURES * LDB];
    const int f = blockIdx.x, t = threadIdx.x, lane = t & 63, wid = t >> 6;
    {
        const int col = lane, gcol = f + col;
        const bool valid = (gcol < IN_FEATURES);
        const float* xp = x + gcol;
        #pragma unroll 8
        for (int i = 0; i < 64; ++i) {
            const int row = wid + i * 4;
            float v = valid ? xp[(size_t)row * IN_FEATURES] : 0.0f;
            As[row * LDA + col] = __float2bfloat16(v);
        }
    }
    {
        const float* wf = w + (size_t)f * (KERNEL_SIZE * LOCAL_FEATURES);
        #pragma unroll
        for (int v4 = 0; v4 < 2; ++v4) {
            const int e0 = (t + v4 * 256) * 4;
            const float4 val = *reinterpret_cast<const float4*>(wf + e0);
            const int k = e0 >> 5, n = e0 & 31;
            Bs[(n + 0) * LDB + k] = __float2bfloat16(val.x);
            Bs[(n + 1) * LDB + k] = __float2bfloat16(val.y);
            Bs[(n + 2) * LDB + k] = __float2bfloat16(val.z);
            Bs[(n + 3) * LDB + k] = __float2bfloat16(val.w);
        }
    }
    __syncthreads();
    f32x4 acc[4][2];
    #pragma unroll
    for (int mt = 0; mt < 4; ++mt)
        #pragma unroll
        for (int nt = 0; nt < 2; ++nt) acc[mt][nt] = (f32x4){0.f,0.f,0.f,0.f};
    const int lrow = lane & 15, kgrp = lane >> 4;
    #pragma unroll
    for (int ks = 0; ks < 2; ++ks) {
        const int kbase = ks * 32 + kgrp * 8;
        bf16x8 bfrag[2], afrag[4];
        #pragma unroll
        for (int nt = 0; nt < 2; ++nt)
            bfrag[nt] = *reinterpret_cast<const bf16x8*>(&Bs[(nt*16+lrow) * LDB + kbase]);
        #pragma unroll
        for (int mt = 0; mt < 4; ++mt)
            afrag[mt] = *reinterpret_cast<const bf16x8*>(&As[(wid*64+mt*16+lrow) * LDA + kbase]);
        #pragma unroll
        for (int mt = 0; mt < 4; ++mt)
            #pragma unroll
            for (int nt = 0; nt < 2; ++nt)
                acc[mt][nt] = __builtin_amdgcn_mfma_f32_16x16x32_bf16(
                    afrag[mt], bfrag[nt], acc[mt][nt], 0, 0, 0);
    }
    float bv[2];
    bv[0] = bias[f * 32 + lrow];
    bv[1] = bias[f * 32 + 16 + lrow];
    #pragma unroll
    for (int mt = 0; mt < 4; ++mt)
        #pragma unroll
        for (int nt = 0; nt < 2; ++nt) {
            const int n = nt * 16 + lrow;
            #pragma unroll
            for (int r = 0; r < 4; ++r) {
                const int b = wid * 64 + mt * 16 + kgrp * 4 + r;
                out[((size_t)b * FOLD_NUM + f) * 32 + n] = acc[mt][nt][r] + bv[nt];
            }
        }
}

extern "C" void kernel_launch(void* const* d_in, const int* in_sizes, int n_in,
                              void* d_out, int out_size, void* d_ws, size_t ws_size,
                              hipStream_t stream) {
    const float* x    = (const float*)d_in[0];
    const float* wgt  = (const float*)d_in[1];
    const float* bias = (const float*)d_in[2];
    float* out        = (float*)d_out;

    const size_t WS_X = (size_t)BATCH * XROW * sizeof(bf16);          // 2,146,304 B
    const size_t WS_W = (size_t)FOLD_NUM * 32 * KPAD * sizeof(bf16);  // 25,165,824 B

    if (ws_size >= WS_X + WS_W) {
        bf16* xb = (bf16*)d_ws;
        bf16* wt = (bf16*)((char*)d_ws + WS_X);
        prep_kernel<<<2048 + 524, 256, 0, stream>>>(x, wgt, xb, wt);
        local_linear_main<<<1024, 512, 0, stream>>>(xb, wt, bias, out);
    } else {
        local_linear_kernel<<<FOLD_NUM, 256, 0, stream>>>(x, wgt, bias, out);
    }
}